// Round 4
// baseline (163.453 us; speedup 1.0000x reference)
//
#include <hip/hip_runtime.h>
#include <hip/hip_bf16.h>

typedef __bf16 bf16_t;
typedef __bf16 bf16x8 __attribute__((ext_vector_type(8)));
typedef __bf16 bf16x4 __attribute__((ext_vector_type(4)));
typedef float  f32x4  __attribute__((ext_vector_type(4)));

#define LN_EPS 1e-5f

// B=8, T=512, C=768 -> M = 4096, 4C = 3072

// ---------------- async global->LDS helper (16B per lane, wave-uniform LDS base) ----
typedef __attribute__((address_space(1))) void gvoid_t;
typedef __attribute__((address_space(3))) void lvoid_t;
__device__ __forceinline__ void glds16(const void* g, void* l) {
    __builtin_amdgcn_global_load_lds((gvoid_t*)g, (lvoid_t*)l, 16, 0, 0);
}

// ---------------- fp32 -> bf16 conversion ----------------
__global__ __launch_bounds__(256) void k_cvt4(const float* __restrict__ s0,
                                              const float* __restrict__ s1,
                                              const float* __restrict__ s2,
                                              const float* __restrict__ s3,
                                              bf16_t* __restrict__ dst, int n4) {
    const float* s = (blockIdx.y == 0) ? s0 : (blockIdx.y == 1) ? s1 : (blockIdx.y == 2) ? s2 : s3;
    bf16_t* d = dst + (size_t)blockIdx.y * ((size_t)n4 * 4);
    int i = blockIdx.x * 256 + threadIdx.x;
    if (i < n4) {
        float4 v = ((const float4*)s)[i];
        bf16x4 o;
        o.x = (bf16_t)v.x; o.y = (bf16_t)v.y; o.z = (bf16_t)v.z; o.w = (bf16_t)v.w;
        ((bf16x4*)d)[i] = o;
    }
}

__global__ __launch_bounds__(256) void k_cvt2(const float* __restrict__ s0,
                                              const float* __restrict__ s1,
                                              bf16_t* __restrict__ dst, int n4) {
    const float* s = (blockIdx.y == 0) ? s0 : s1;
    bf16_t* d = dst + (size_t)blockIdx.y * ((size_t)n4 * 4);
    int i = blockIdx.x * 256 + threadIdx.x;
    if (i < n4) {
        float4 v = ((const float4*)s)[i];
        bf16x4 o;
        o.x = (bf16_t)v.x; o.y = (bf16_t)v.y; o.z = (bf16_t)v.z; o.w = (bf16_t)v.w;
        ((bf16x4*)d)[i] = o;
    }
}

// ---------------- LayerNorm (one block per row of C=768), bf16 out ----------------
__global__ __launch_bounds__(256) void k_ln(const float* __restrict__ x,
                                            const float* __restrict__ w,
                                            const float* __restrict__ b,
                                            bf16_t* __restrict__ out, int C) {
    int row = blockIdx.x;
    const float* xr = x + (long)row * C;
    int tid = threadIdx.x;
    float s = 0.f, s2 = 0.f;
    for (int i = tid; i < C; i += 256) { float v = xr[i]; s += v; s2 += v * v; }
    for (int m = 32; m; m >>= 1) { s += __shfl_xor(s, m, 64); s2 += __shfl_xor(s2, m, 64); }
    __shared__ float red[8];
    int wv = tid >> 6;
    if ((tid & 63) == 0) { red[wv] = s; red[4 + wv] = s2; }
    __syncthreads();
    float ts  = red[0] + red[1] + red[2] + red[3];
    float ts2 = red[4] + red[5] + red[6] + red[7];
    float mu  = ts / C;
    float var = ts2 / C - mu * mu;
    float rstd = rsqrtf(var + LN_EPS);
    bf16_t* orow = out + (long)row * C;
    for (int i = tid; i < C; i += 256)
        orow[i] = (bf16_t)((xr[i] - mu) * rstd * w[i] + b[i]);
}

// ---------------- bf16 MFMA GEMM, 3-buffer counted-vmcnt pipeline ----------------
// C[M][N](+=) A[M][K-slice] * Bw[N][K-slice]^T, 128x128 tile, 4 waves, BK=32,
// Kloc = 768 per block (24 iters). Split-K via nks (EPI 3 accumulates atomically).
// Per iter: s_waitcnt vmcnt(4) [newest stage stays in flight] ; s_barrier ;
//           STAGE(tile+2) ; COMPUTE(cur).  Never drains vmcnt to 0 in the loop.
// LDS bank-swizzle: linear glds16 dest, pre-swizzled global source col, swizzled read.
// EPI 0: store bf16   EPI 1: store bf16(relu^2)   EPI 3: atomicAdd fp32
template <int EPI>
__global__ __launch_bounds__(256) void k_gemm_bt(const bf16_t* __restrict__ A,
                                                 const bf16_t* __restrict__ Bw,
                                                 void* __restrict__ Cout,
                                                 int N, int Ktot, int nbn, int nks) {
    constexpr int TBUF = 128 * 32;                    // elements per (A or B) buffer
    __shared__ __align__(16) bf16_t As[3][128][32];   // 24 KB
    __shared__ __align__(16) bf16_t Bs[3][128][32];   // 24 KB
    const int tid  = threadIdx.x;
    const int lane = tid & 63, wid = tid >> 6;
    const int wm = (wid >> 1) * 64, wn = (wid & 1) * 64;

    // XCD-aware block swizzle (nwg % 8 == 0 for all launches here)
    int nwg = gridDim.x;
    int cpx = nwg >> 3;
    int bid = blockIdx.x;
    int swz = (bid & 7) * cpx + (bid >> 3);
    int per_m = nbn * nks;
    int bm  = swz / per_m;
    int rem = swz % per_m;
    int ks  = rem / nbn;
    int bn  = rem % nbn;

    const int fr = lane & 15;
    const int swcol = ((lane >> 4) ^ (fr & 3)) * 8;   // swizzled read column (elems)

    f32x4 acc[4][4];
#pragma unroll
    for (int i = 0; i < 4; i++)
#pragma unroll
        for (int j = 0; j < 4; j++) acc[i][j] = (f32x4){0.f, 0.f, 0.f, 0.f};

    // staging: wave stages 16 rows x 32 cols per glds16; lane l -> LDS byte l*16
    //   slot (r = l>>2, g = l&3) holds logical colgroup g ^ (r&3)  (bank swizzle)
    const int srow = wid * 16 + (lane >> 2);
    const int scol = ((lane & 3) ^ ((lane >> 2) & 3)) * 8;   // pre-swizzled source col
    const bf16_t* Ag = A  + (size_t)(bm * 128 + srow) * Ktot + (size_t)ks * 768 + scol;
    const bf16_t* Bg = Bw + (size_t)(bn * 128 + srow) * Ktot + (size_t)ks * 768 + scol;
    const size_t rowK64 = (size_t)64 * Ktot;
    bf16_t* lA = &As[0][wid * 16][0];    // wave-uniform LDS bases
    bf16_t* lB = &Bs[0][wid * 16][0];

#define STAGE(buf, kt)                                              \
    do {                                                            \
        glds16(Ag + (kt),          lA + (buf) * TBUF);              \
        glds16(Ag + (kt) + rowK64, lA + (buf) * TBUF + 64 * 32);    \
        glds16(Bg + (kt),          lB + (buf) * TBUF);              \
        glds16(Bg + (kt) + rowK64, lB + (buf) * TBUF + 64 * 32);    \
    } while (0)

#define COMPUTE(buf)                                                                         \
    do {                                                                                     \
        bf16x8 af[4], bfr[4];                                                                \
        _Pragma("unroll")                                                                    \
        for (int mi = 0; mi < 4; mi++) af[mi] = *(const bf16x8*)&As[buf][wm + mi * 16 + fr][swcol]; \
        _Pragma("unroll")                                                                    \
        for (int ni = 0; ni < 4; ni++) bfr[ni] = *(const bf16x8*)&Bs[buf][wn + ni * 16 + fr][swcol]; \
        _Pragma("unroll")                                                                    \
        for (int mi = 0; mi < 4; mi++)                                                       \
            _Pragma("unroll")                                                                \
            for (int ni = 0; ni < 4; ni++)                                                   \
                acc[mi][ni] = __builtin_amdgcn_mfma_f32_16x16x32_bf16(af[mi], bfr[ni], acc[mi][ni], 0, 0, 0); \
    } while (0)

    // NT = 24 tiles of BK=32 (Kloc = 768)
    STAGE(0, 0);
    STAGE(1, 32);
    int ba = 0, bb = 1, bc = 2;
    for (int it = 0; it < 22; ++it) {
        asm volatile("s_waitcnt vmcnt(4)" ::: "memory");  // oldest stage (cur tile) done
        __builtin_amdgcn_s_barrier();
        __builtin_amdgcn_sched_barrier(0);
        STAGE(bc, (it + 2) * 32);
        COMPUTE(ba);
        int t = ba; ba = bb; bb = bc; bc = t;
    }
    asm volatile("s_waitcnt vmcnt(4)" ::: "memory");
    __builtin_amdgcn_s_barrier();
    __builtin_amdgcn_sched_barrier(0);
    COMPUTE(ba);
    asm volatile("s_waitcnt vmcnt(0)" ::: "memory");
    __builtin_amdgcn_s_barrier();
    __builtin_amdgcn_sched_barrier(0);
    COMPUTE(bb);

#undef STAGE
#undef COMPUTE

    const int row0 = bm * 128 + wm, col0 = bn * 128 + wn;
#pragma unroll
    for (int mi = 0; mi < 4; mi++) {
#pragma unroll
        for (int ni = 0; ni < 4; ni++) {
            int row = row0 + mi * 16 + (lane >> 4) * 4;   // C/D: col=lane&15, row=(lane>>4)*4+r
            int col = col0 + ni * 16 + (lane & 15);
#pragma unroll
            for (int r = 0; r < 4; r++) {
                float val = acc[mi][ni][r];
                size_t off = (size_t)(row + r) * N + col;
                if (EPI == 0) {
                    ((bf16_t*)Cout)[off] = (bf16_t)val;
                } else if (EPI == 1) {
                    float t = fmaxf(val, 0.f);
                    ((bf16_t*)Cout)[off] = (bf16_t)(t * t);
                } else {
                    atomicAdd(&((float*)Cout)[off], val);
                }
            }
        }
    }
}

// ---------------- WKV chunked scan (y4 bf16) ----------------
// y4 layout per (b,t): [ r(768) | k(768) | v(768) | router(768) ]
__global__ __launch_bounds__(256) void k_scan_local(const bf16_t* __restrict__ y4,
                                                    const float* __restrict__ tmw,
                                                    float* __restrict__ wkvl,
                                                    float* __restrict__ states) {
    int idx = blockIdx.x * 256 + threadIdx.x;  // (b*16 + ch)*768 + c
    int c   = idx % 768;
    int rem = idx / 768;
    int ch  = rem & 15;
    int b   = rem >> 4;
    float d = expf(-expf(tmw[c]));
    const bf16_t* base = y4 + ((size_t)(b * 512 + ch * 32)) * 3072 + c;
    float*        wout = wkvl + ((size_t)(b * 512 + ch * 32)) * 768 + c;
    float s = 0.f;
#pragma unroll 4
    for (int i = 0; i < 32; i++) {
        float kk = (float)base[(size_t)i * 3072 + 768];
        float vv = (float)base[(size_t)i * 3072 + 1536];
        s = s * d + kk * vv;
        wout[(size_t)i * 768] = s;
    }
    states[idx] = s;
}

__global__ __launch_bounds__(256) void k_scan_carry(const float* __restrict__ states,
                                                    const float* __restrict__ tmw,
                                                    float* __restrict__ carries) {
    int idx = blockIdx.x * 256 + threadIdx.x;  // b*768 + c
    int c = idx % 768, b = idx / 768;
    float dL = expf(-expf(tmw[c]) * 32.f);
    float s = 0.f;
    for (int ch = 0; ch < 16; ch++) {
        size_t o = ((size_t)(b * 16 + ch)) * 768 + c;
        carries[o] = s;
        s = s * dL + states[o];
    }
}

// ---------------- mix + LN2 fused: one block per (b,t) row ----------------
// out = x + r*((wkv_local + carry*d^(tmod+1)) * sigmoid(router));  xx2 = LN2(out) bf16
// (out is d_out; the final GEMM atomically adds the channel-mix on top)
__global__ __launch_bounds__(256) void k_mix_ln(const bf16_t* __restrict__ y4,
                                                const float* __restrict__ wkvl,
                                                const float* __restrict__ carries,
                                                const float* __restrict__ tmw,
                                                const float* __restrict__ x,
                                                const float* __restrict__ w2,
                                                const float* __restrict__ b2,
                                                float* __restrict__ out,
                                                bf16_t* __restrict__ xx2) {
    int bt = blockIdx.x;
    int t = bt & 511, b = bt >> 9;
    int tid = threadIdx.x;
    const bf16_t* yrow = y4 + (size_t)bt * 3072;
    const float*  wl   = wkvl + (size_t)bt * 768;
    const float*  cr   = carries + ((size_t)(b * 16) + (t >> 5)) * 768;
    const float*  xr   = x + (size_t)bt * 768;
    float tn = (float)((t & 31) + 1);

    float vals[3];
    float s = 0.f, s2 = 0.f;
#pragma unroll
    for (int j = 0; j < 3; j++) {
        int c = tid + j * 256;
        float rr = (float)yrow[c];
        float gg = (float)yrow[c + 2304];
        float wk = wl[c] + cr[c] * expf(-expf(tmw[c]) * tn);
        float sig = 1.f / (1.f + expf(-gg));
        float o = fmaf(rr, wk * sig, xr[c]);
        vals[j] = o; s += o; s2 += o * o;
    }
    for (int m = 32; m; m >>= 1) { s += __shfl_xor(s, m, 64); s2 += __shfl_xor(s2, m, 64); }
    __shared__ float red[8];
    int wv = tid >> 6;
    if ((tid & 63) == 0) { red[wv] = s; red[4 + wv] = s2; }
    __syncthreads();
    float ts  = red[0] + red[1] + red[2] + red[3];
    float ts2 = red[4] + red[5] + red[6] + red[7];
    float mu  = ts * (1.f / 768.f);
    float var = ts2 * (1.f / 768.f) - mu * mu;
    float rstd = rsqrtf(var + LN_EPS);
    float* orow = out + (size_t)bt * 768;
    bf16_t* xo = xx2 + (size_t)bt * 768;
#pragma unroll
    for (int j = 0; j < 3; j++) {
        int c = tid + j * 256;
        orow[c] = vals[j];
        xo[c] = (bf16_t)((vals[j] - mu) * rstd * w2[c] + b2[c]);
    }
}

// ---------------- host-side launch ----------------
extern "C" void kernel_launch(void* const* d_in, const int* in_sizes, int n_in,
                              void* d_out, int out_size, void* d_ws, size_t ws_size,
                              hipStream_t stream) {
    const float* x    = (const float*)d_in[0];
    const float* ln1w = (const float*)d_in[1];
    const float* ln1b = (const float*)d_in[2];
    const float* Wr   = (const float*)d_in[3];
    const float* Wk   = (const float*)d_in[4];
    const float* Wv   = (const float*)d_in[5];
    const float* tmw  = (const float*)d_in[6];
    const float* Wrt  = (const float*)d_in[7];
    const float* ln2w = (const float*)d_in[8];
    const float* ln2b = (const float*)d_in[9];
    const float* Wck  = (const float*)d_in[10];
    const float* Wcv  = (const float*)d_in[11];
    float* out = (float*)d_out;
    char* ws = (char*)d_ws;

    // workspace layout (bytes)
    bf16_t* xx     = (bf16_t*)(ws + 0);          // 4096*768 bf16 (xx, reused as xx2)
    bf16_t* wcat   = (bf16_t*)(ws + 6291456);    // [4][768][768] bf16 (r,k,v,router)
    bf16_t* wckb   = (bf16_t*)(ws + 11010048);   // [3072][768] bf16
    bf16_t* wcvb   = (bf16_t*)(ws + 15728640);   // [768][3072] bf16
    bf16_t* y4     = (bf16_t*)(ws + 20447232);   // [4096][3072] bf16
    bf16_t* kcm    = (bf16_t*)(ws + 20447232);   // reuses y4 after mix
    float*  wkvl   = (float*)(ws + 70778880);    // [4096][768] fp32
    float*  states = (float*)(ws + 83361792);    // [8][16][768]
    float*  carr   = (float*)(ws + 83755008);    // [8][16][768]

    // 1) weights -> bf16
    const int n768 = 768 * 768 / 4;
    const int nbig = 3072 * 768 / 4;
    k_cvt4<<<dim3(576, 4), dim3(256), 0, stream>>>(Wr, Wk, Wv, Wrt, wcat, n768);
    k_cvt2<<<dim3(2304, 2), dim3(256), 0, stream>>>(Wck, Wcv, wckb, nbig);

    // 2) LN1
    k_ln<<<dim3(4096), dim3(256), 0, stream>>>(x, ln1w, ln1b, xx, 768);

    // 3) fused r|k|v|router GEMM: y4 = xx @ wcat^T  (M=4096, N=3072, Ktot=768)
    k_gemm_bt<0><<<dim3(768), dim3(256), 0, stream>>>(xx, wcat, (void*)y4, 3072, 768, 24, 1);

    // 4) wkv scan + mix(+LN2): writes x1 -> d_out, xx2 -> xx
    k_scan_local<<<dim3(384), dim3(256), 0, stream>>>(y4, tmw, wkvl, states);
    k_scan_carry<<<dim3(24), dim3(256), 0, stream>>>(states, tmw, carr);
    k_mix_ln<<<dim3(4096), dim3(256), 0, stream>>>(y4, wkvl, carr, tmw, x, ln2w, ln2b, out, xx);

    // 5) k_cm = bf16(relu(xx2 @ Wck^T)^2)  (M=4096, N=3072, Ktot=768)
    k_gemm_bt<1><<<dim3(768), dim3(256), 0, stream>>>(xx, wckb, (void*)kcm, 3072, 768, 24, 1);

    // 6) out += k_cm @ Wcv^T  (M=4096, N=768, Ktot=3072), split-K=4, fp32 atomics
    k_gemm_bt<3><<<dim3(768), dim3(256), 0, stream>>>(kcm, wcvb, (void*)out, 768, 3072, 6, 4);
}

// Round 5
// 157.969 us; speedup vs baseline: 1.0347x; 1.0347x over previous
//
#include <hip/hip_runtime.h>
#include <hip/hip_bf16.h>

typedef __bf16 bf16_t;
typedef __bf16 bf16x8 __attribute__((ext_vector_type(8)));
typedef __bf16 bf16x4 __attribute__((ext_vector_type(4)));
typedef float  f32x4  __attribute__((ext_vector_type(4)));

#define LN_EPS 1e-5f

// B=8, T=512, C=768 -> M = 4096, 4C = 3072

// ---------------- async global->LDS helper (16B per lane, wave-uniform LDS base) ----
typedef __attribute__((address_space(1))) void gvoid_t;
typedef __attribute__((address_space(3))) void lvoid_t;
__device__ __forceinline__ void glds16(const void* g, void* l) {
    __builtin_amdgcn_global_load_lds((gvoid_t*)g, (lvoid_t*)l, 16, 0, 0);
}

// ---------------- fp32 -> bf16 conversion ----------------
__global__ __launch_bounds__(256) void k_cvt4(const float* __restrict__ s0,
                                              const float* __restrict__ s1,
                                              const float* __restrict__ s2,
                                              const float* __restrict__ s3,
                                              bf16_t* __restrict__ dst, int n4) {
    const float* s = (blockIdx.y == 0) ? s0 : (blockIdx.y == 1) ? s1 : (blockIdx.y == 2) ? s2 : s3;
    bf16_t* d = dst + (size_t)blockIdx.y * ((size_t)n4 * 4);
    int i = blockIdx.x * 256 + threadIdx.x;
    if (i < n4) {
        float4 v = ((const float4*)s)[i];
        bf16x4 o;
        o.x = (bf16_t)v.x; o.y = (bf16_t)v.y; o.z = (bf16_t)v.z; o.w = (bf16_t)v.w;
        ((bf16x4*)d)[i] = o;
    }
}

__global__ __launch_bounds__(256) void k_cvt2(const float* __restrict__ s0,
                                              const float* __restrict__ s1,
                                              bf16_t* __restrict__ dst, int n4) {
    const float* s = (blockIdx.y == 0) ? s0 : s1;
    bf16_t* d = dst + (size_t)blockIdx.y * ((size_t)n4 * 4);
    int i = blockIdx.x * 256 + threadIdx.x;
    if (i < n4) {
        float4 v = ((const float4*)s)[i];
        bf16x4 o;
        o.x = (bf16_t)v.x; o.y = (bf16_t)v.y; o.z = (bf16_t)v.z; o.w = (bf16_t)v.w;
        ((bf16x4*)d)[i] = o;
    }
}

// ---------------- LayerNorm (one block per row of C=768), bf16 out ----------------
__global__ __launch_bounds__(256) void k_ln(const float* __restrict__ x,
                                            const float* __restrict__ w,
                                            const float* __restrict__ b,
                                            bf16_t* __restrict__ out, int C) {
    int row = blockIdx.x;
    const float* xr = x + (long)row * C;
    int tid = threadIdx.x;
    float s = 0.f, s2 = 0.f;
    for (int i = tid; i < C; i += 256) { float v = xr[i]; s += v; s2 += v * v; }
    for (int m = 32; m; m >>= 1) { s += __shfl_xor(s, m, 64); s2 += __shfl_xor(s2, m, 64); }
    __shared__ float red[8];
    int wv = tid >> 6;
    if ((tid & 63) == 0) { red[wv] = s; red[4 + wv] = s2; }
    __syncthreads();
    float ts  = red[0] + red[1] + red[2] + red[3];
    float ts2 = red[4] + red[5] + red[6] + red[7];
    float mu  = ts / C;
    float var = ts2 / C - mu * mu;
    float rstd = rsqrtf(var + LN_EPS);
    bf16_t* orow = out + (long)row * C;
    for (int i = tid; i < C; i += 256)
        orow[i] = (bf16_t)((xr[i] - mu) * rstd * w[i] + b[i]);
}

// ---------------- bf16 MFMA GEMM, 8-wave 128x128 tile, 3-buffer counted-vmcnt ------
// C[M][N](+=) A[M][Kslice] * Bw[N][Kslice]^T.  512 threads = 8 waves (2M x 4N),
// each wave owns 64x32 out (acc 4x2), BK=32, Kloc=768 (24 tiles).
// Pipeline: STAGE(t+2) in flight; per iter s_waitcnt vmcnt(2) (own 2 loads of the
// current tile) + raw s_barrier; never drains vmcnt to 0 in the loop.
// LDS swizzle (2-way max, free): slot holds logical colgroup slot^((row>>2)&3);
// stage pre-swizzles the GLOBAL source col (LDS dest stays linear, rule 21).
// XCD slab swizzle: grid 768, each XCD gets an 8(bm) x 12(col) slab -> L2 set ~3.9MB.
// EPI 0: store bf16   EPI 1: store bf16(relu^2)   EPI 3: atomicAdd fp32
template <int EPI>
__global__ __launch_bounds__(512, 6) void k_gemm_bt(const bf16_t* __restrict__ A,
                                                    const bf16_t* __restrict__ Bw,
                                                    void* __restrict__ Cout,
                                                    int N, int Ktot, int nbn, int nks) {
    constexpr int TBUF = 128 * 32;                    // elements per (A or B) buffer
    __shared__ __align__(16) bf16_t As[3][128][32];   // 24 KB
    __shared__ __align__(16) bf16_t Bs[3][128][32];   // 24 KB
    const int tid  = threadIdx.x;
    const int lane = tid & 63, wid = tid >> 6;        // wid 0..7
    const int wm = (wid >> 2) * 64, wn = (wid & 3) * 32;

    // XCD slab swizzle: xcd = bid%8 (HW round-robin); slab = 8 bm x 12 cols.
    // Requires grid == 768 and (nbn*nks) == 24 (true for all launches here).
    int bid = blockIdx.x;
    int xcd = bid & 7, loc = bid >> 3;                // loc 0..95
    int lb = loc / 12, lc = loc % 12;
    int swz = ((xcd >> 1) * 8 + lb) * 24 + (xcd & 1) * 12 + lc;
    int per_m = nbn * nks;
    int bm  = swz / per_m;
    int rem = swz % per_m;
    int ks  = rem / nbn;
    int bn  = rem % nbn;

    const int fr = lane & 15;
    // read: physical slot = logical_group ^ ((row>>2)&3); row%16 == fr always
    const int swcol = (((lane >> 4) ^ ((lane >> 2) & 3)) & 3) * 8;

    f32x4 acc[4][2];
#pragma unroll
    for (int i = 0; i < 4; i++)
#pragma unroll
        for (int j = 0; j < 2; j++) acc[i][j] = (f32x4){0.f, 0.f, 0.f, 0.f};

    // staging: wave w stages rows [w*16, w*16+16) of A and of B (1 glds16 each).
    // lane l -> LDS byte base+16l = row l>>2, slot l&3; source colgroup = slot^((row>>2)&3)
    const int srow = wid * 16 + (lane >> 2);
    const int scol = (((lane & 3) ^ ((lane >> 4) & 3)) & 3) * 8;  // (row>>2)&3 == (lane>>4)&3
    const bf16_t* Ag = A  + (size_t)(bm * 128 + srow) * Ktot + (size_t)ks * 768 + scol;
    const bf16_t* Bg = Bw + (size_t)(bn * 128 + srow) * Ktot + (size_t)ks * 768 + scol;
    bf16_t* lA = &As[0][wid * 16][0];    // wave-uniform LDS bases
    bf16_t* lB = &Bs[0][wid * 16][0];

#define STAGE(buf, kt)                                  \
    do {                                                \
        glds16(Ag + (kt), lA + (buf) * TBUF);           \
        glds16(Bg + (kt), lB + (buf) * TBUF);           \
    } while (0)

#define COMPUTE(buf)                                                                         \
    do {                                                                                     \
        bf16x8 af[4], bfr[2];                                                                \
        _Pragma("unroll")                                                                    \
        for (int mi = 0; mi < 4; mi++) af[mi] = *(const bf16x8*)&As[buf][wm + mi * 16 + fr][swcol]; \
        _Pragma("unroll")                                                                    \
        for (int ni = 0; ni < 2; ni++) bfr[ni] = *(const bf16x8*)&Bs[buf][wn + ni * 16 + fr][swcol]; \
        __builtin_amdgcn_s_setprio(1);                                                       \
        _Pragma("unroll")                                                                    \
        for (int mi = 0; mi < 4; mi++)                                                       \
            _Pragma("unroll")                                                                \
            for (int ni = 0; ni < 2; ni++)                                                   \
                acc[mi][ni] = __builtin_amdgcn_mfma_f32_16x16x32_bf16(af[mi], bfr[ni], acc[mi][ni], 0, 0, 0); \
        __builtin_amdgcn_s_setprio(0);                                                       \
    } while (0)

    // 24 tiles of BK=32 (Kloc = 768)
    STAGE(0, 0);
    STAGE(1, 32);
    int ba = 0, bb = 1, bc = 2;
    for (int it = 0; it < 22; ++it) {
        asm volatile("s_waitcnt vmcnt(2)" ::: "memory");  // own loads of current tile done
        __builtin_amdgcn_s_barrier();
        __builtin_amdgcn_sched_barrier(0);
        STAGE(bc, (it + 2) * 32);
        COMPUTE(ba);
        int t = ba; ba = bb; bb = bc; bc = t;
    }
    asm volatile("s_waitcnt vmcnt(2)" ::: "memory");
    __builtin_amdgcn_s_barrier();
    __builtin_amdgcn_sched_barrier(0);
    COMPUTE(ba);
    asm volatile("s_waitcnt vmcnt(0)" ::: "memory");
    __builtin_amdgcn_s_barrier();
    __builtin_amdgcn_sched_barrier(0);
    COMPUTE(bb);

#undef STAGE
#undef COMPUTE

    const int row0 = bm * 128 + wm, col0 = bn * 128 + wn;
#pragma unroll
    for (int mi = 0; mi < 4; mi++) {
#pragma unroll
        for (int ni = 0; ni < 2; ni++) {
            int row = row0 + mi * 16 + (lane >> 4) * 4;   // C/D: col=lane&15, row=(lane>>4)*4+r
            int col = col0 + ni * 16 + (lane & 15);
#pragma unroll
            for (int r = 0; r < 4; r++) {
                float val = acc[mi][ni][r];
                size_t off = (size_t)(row + r) * N + col;
                if (EPI == 0) {
                    ((bf16_t*)Cout)[off] = (bf16_t)val;
                } else if (EPI == 1) {
                    float t = fmaxf(val, 0.f);
                    ((bf16_t*)Cout)[off] = (bf16_t)(t * t);
                } else {
                    atomicAdd(&((float*)Cout)[off], val);
                }
            }
        }
    }
}

// ---------------- WKV chunked scan (y4 bf16) ----------------
// y4 layout per (b,t): [ r(768) | k(768) | v(768) | router(768) ]
__global__ __launch_bounds__(256) void k_scan_local(const bf16_t* __restrict__ y4,
                                                    const float* __restrict__ tmw,
                                                    float* __restrict__ wkvl,
                                                    float* __restrict__ states) {
    int idx = blockIdx.x * 256 + threadIdx.x;  // (b*16 + ch)*768 + c
    int c   = idx % 768;
    int rem = idx / 768;
    int ch  = rem & 15;
    int b   = rem >> 4;
    float d = expf(-expf(tmw[c]));
    const bf16_t* base = y4 + ((size_t)(b * 512 + ch * 32)) * 3072 + c;
    float*        wout = wkvl + ((size_t)(b * 512 + ch * 32)) * 768 + c;
    float s = 0.f;
#pragma unroll 4
    for (int i = 0; i < 32; i++) {
        float kk = (float)base[(size_t)i * 3072 + 768];
        float vv = (float)base[(size_t)i * 3072 + 1536];
        s = s * d + kk * vv;
        wout[(size_t)i * 768] = s;
    }
    states[idx] = s;
}

__global__ __launch_bounds__(256) void k_scan_carry(const float* __restrict__ states,
                                                    const float* __restrict__ tmw,
                                                    float* __restrict__ carries) {
    int idx = blockIdx.x * 256 + threadIdx.x;  // b*768 + c
    int c = idx % 768, b = idx / 768;
    float dL = expf(-expf(tmw[c]) * 32.f);
    float s = 0.f;
    for (int ch = 0; ch < 16; ch++) {
        size_t o = ((size_t)(b * 16 + ch)) * 768 + c;
        carries[o] = s;
        s = s * dL + states[o];
    }
}

// ---------------- mix + LN2 fused: one block per (b,t) row ----------------
// out = x + r*((wkv_local + carry*d^(tmod+1)) * sigmoid(router));  xx2 = LN2(out) bf16
// (out is d_out; the final GEMM atomically adds the channel-mix on top)
__global__ __launch_bounds__(256) void k_mix_ln(const bf16_t* __restrict__ y4,
                                                const float* __restrict__ wkvl,
                                                const float* __restrict__ carries,
                                                const float* __restrict__ tmw,
                                                const float* __restrict__ x,
                                                const float* __restrict__ w2,
                                                const float* __restrict__ b2,
                                                float* __restrict__ out,
                                                bf16_t* __restrict__ xx2) {
    int bt = blockIdx.x;
    int t = bt & 511, b = bt >> 9;
    int tid = threadIdx.x;
    const bf16_t* yrow = y4 + (size_t)bt * 3072;
    const float*  wl   = wkvl + (size_t)bt * 768;
    const float*  cr   = carries + ((size_t)(b * 16) + (t >> 5)) * 768;
    const float*  xr   = x + (size_t)bt * 768;
    float tn = (float)((t & 31) + 1);

    float vals[3];
    float s = 0.f, s2 = 0.f;
#pragma unroll
    for (int j = 0; j < 3; j++) {
        int c = tid + j * 256;
        float rr = (float)yrow[c];
        float gg = (float)yrow[c + 2304];
        float wk = wl[c] + cr[c] * expf(-expf(tmw[c]) * tn);
        float sig = 1.f / (1.f + expf(-gg));
        float o = fmaf(rr, wk * sig, xr[c]);
        vals[j] = o; s += o; s2 += o * o;
    }
    for (int m = 32; m; m >>= 1) { s += __shfl_xor(s, m, 64); s2 += __shfl_xor(s2, m, 64); }
    __shared__ float red[8];
    int wv = tid >> 6;
    if ((tid & 63) == 0) { red[wv] = s; red[4 + wv] = s2; }
    __syncthreads();
    float ts  = red[0] + red[1] + red[2] + red[3];
    float ts2 = red[4] + red[5] + red[6] + red[7];
    float mu  = ts * (1.f / 768.f);
    float var = ts2 * (1.f / 768.f) - mu * mu;
    float rstd = rsqrtf(var + LN_EPS);
    float* orow = out + (size_t)bt * 768;
    bf16_t* xo = xx2 + (size_t)bt * 768;
#pragma unroll
    for (int j = 0; j < 3; j++) {
        int c = tid + j * 256;
        orow[c] = vals[j];
        xo[c] = (bf16_t)((vals[j] - mu) * rstd * w2[c] + b2[c]);
    }
}

// ---------------- host-side launch ----------------
extern "C" void kernel_launch(void* const* d_in, const int* in_sizes, int n_in,
                              void* d_out, int out_size, void* d_ws, size_t ws_size,
                              hipStream_t stream) {
    const float* x    = (const float*)d_in[0];
    const float* ln1w = (const float*)d_in[1];
    const float* ln1b = (const float*)d_in[2];
    const float* Wr   = (const float*)d_in[3];
    const float* Wk   = (const float*)d_in[4];
    const float* Wv   = (const float*)d_in[5];
    const float* tmw  = (const float*)d_in[6];
    const float* Wrt  = (const float*)d_in[7];
    const float* ln2w = (const float*)d_in[8];
    const float* ln2b = (const float*)d_in[9];
    const float* Wck  = (const float*)d_in[10];
    const float* Wcv  = (const float*)d_in[11];
    float* out = (float*)d_out;
    char* ws = (char*)d_ws;

    // workspace layout (bytes)
    bf16_t* xx     = (bf16_t*)(ws + 0);          // 4096*768 bf16 (xx, reused as xx2)
    bf16_t* wcat   = (bf16_t*)(ws + 6291456);    // [4][768][768] bf16 (r,k,v,router)
    bf16_t* wckb   = (bf16_t*)(ws + 11010048);   // [3072][768] bf16
    bf16_t* wcvb   = (bf16_t*)(ws + 15728640);   // [768][3072] bf16
    bf16_t* y4     = (bf16_t*)(ws + 20447232);   // [4096][3072] bf16
    bf16_t* kcm    = (bf16_t*)(ws + 20447232);   // reuses y4 after mix
    float*  wkvl   = (float*)(ws + 70778880);    // [4096][768] fp32
    float*  states = (float*)(ws + 83361792);    // [8][16][768]
    float*  carr   = (float*)(ws + 83755008);    // [8][16][768]

    // 1) weights -> bf16
    const int n768 = 768 * 768 / 4;
    const int nbig = 3072 * 768 / 4;
    k_cvt4<<<dim3(576, 4), dim3(256), 0, stream>>>(Wr, Wk, Wv, Wrt, wcat, n768);
    k_cvt2<<<dim3(2304, 2), dim3(256), 0, stream>>>(Wck, Wcv, wckb, nbig);

    // 2) LN1
    k_ln<<<dim3(4096), dim3(256), 0, stream>>>(x, ln1w, ln1b, xx, 768);

    // 3) fused r|k|v|router GEMM: y4 = xx @ wcat^T  (M=4096, N=3072, Ktot=768)
    k_gemm_bt<0><<<dim3(768), dim3(512), 0, stream>>>(xx, wcat, (void*)y4, 3072, 768, 24, 1);

    // 4) wkv scan + mix(+LN2): writes x1 -> d_out, xx2 -> xx
    k_scan_local<<<dim3(384), dim3(256), 0, stream>>>(y4, tmw, wkvl, states);
    k_scan_carry<<<dim3(24), dim3(256), 0, stream>>>(states, tmw, carr);
    k_mix_ln<<<dim3(4096), dim3(256), 0, stream>>>(y4, wkvl, carr, tmw, x, ln2w, ln2b, out, xx);

    // 5) k_cm = bf16(relu(xx2 @ Wck^T)^2)  (M=4096, N=3072, Ktot=768)
    k_gemm_bt<1><<<dim3(768), dim3(512), 0, stream>>>(xx, wckb, (void*)kcm, 3072, 768, 24, 1);

    // 6) out += k_cm @ Wcv^T  (M=4096, N=768, Ktot=3072), split-K=4, fp32 atomics
    k_gemm_bt<3><<<dim3(768), dim3(512), 0, stream>>>(kcm, wcvb, (void*)out, 768, 3072, 6, 4);
}